// Round 1
// baseline (1004.421 us; speedup 1.0000x reference)
//
#include <hip/hip_runtime.h>
#include <hip/hip_bf16.h>
#include <cstdint>
#include <cstddef>

#define N_NODES 50000
#define N_EDGES 800000

typedef __attribute__((ext_vector_type(8))) short short8;
typedef __attribute__((ext_vector_type(4))) float floatx4;
typedef __attribute__((ext_vector_type(4))) unsigned int uintx4;

__device__ inline float bf2f(unsigned short u) {
    union { unsigned int i; float f; } v; v.i = ((unsigned int)u) << 16; return v.f;
}
__device__ inline unsigned short f2bf(float f) {
    union { float f; unsigned int i; } v; v.f = f;
    unsigned int u = v.i;
    return (unsigned short)((u + 0x7FFFu + ((u >> 16) & 1u)) >> 16);
}
__device__ inline float silu_f(float x) {
    return x / (1.0f + __expf(-x));
}

// ---------------------------------------------------------------------------
// Pack kernel: fp32->bf16 conversions + weight rearrangement into MFMA
// B-fragment order: Bp[(kb*NOUT + n)*8 + i] = B[(kb*8+i)*NOUT + n]
// ---------------------------------------------------------------------------
__device__ inline void pack_std(const float* __restrict__ src,
                                unsigned short* __restrict__ dst,
                                int NOUT, long j) {
    int i = (int)(j & 7);
    long rest = j >> 3;
    int n = (int)(rest % NOUT);
    int kb = (int)(rest / NOUT);
    dst[j] = f2bf(src[(long)(kb * 8 + i) * NOUT + n]);
}

#define NH0   (N_NODES * 64L)
#define SW_IN 8192L
#define SW_OUT 8192L
#define SW1   16384L
#define SE2   4096L
#define SN1   24576L
#define SN2   16384L
#define SB    128L
#define PERL  (SW1 + SE2 + SN1 + SN2 + SB)
#define PACK_TOTAL (NH0 + SW_IN + SW_OUT + 4 * PERL)

__global__ __launch_bounds__(256) void pack_kernel(
    const float* __restrict__ h0, const float* __restrict__ W_in,
    const float* __restrict__ W_out, const float* __restrict__ eW1,
    const float* __restrict__ eb1, const float* __restrict__ eW2,
    const float* __restrict__ nW1, const float* __restrict__ nW2,
    unsigned short* __restrict__ h0bf, unsigned short* __restrict__ Winp,
    unsigned short* __restrict__ Woutp, unsigned short* __restrict__ W1p,
    unsigned short* __restrict__ eW2p, unsigned short* __restrict__ nW1p,
    unsigned short* __restrict__ nW2p, float* __restrict__ biasP)
{
    long idx = (long)blockIdx.x * 256 + threadIdx.x;
    if (idx >= PACK_TOTAL) return;
    long j = idx;
    if (j < NH0) { h0bf[j] = f2bf(h0[j]); return; }
    j -= NH0;
    if (j < SW_IN) { pack_std(W_in, Winp, 128, j); return; }
    j -= SW_IN;
    if (j < SW_OUT) { pack_std(W_out, Woutp, 64, j); return; }
    j -= SW_OUT;
    int l = (int)(j / PERL);
    long r = j % PERL;
    if (r < SW1) {
        // W1' combined: [K=128, NOUT=128]; n<64 -> eW1[k][n] (top rows),
        // n>=64 -> eW1[128+k][n-64] (bottom rows)
        int i = (int)(r & 7);
        int n = (int)((r >> 3) & 127);
        int kb = (int)(r >> 10);
        int k = kb * 8 + i;
        const float* w = eW1 + (long)l * 256 * 64;
        float v = (n < 64) ? w[(long)k * 64 + n] : w[(long)(128 + k) * 64 + (n - 64)];
        W1p[(long)l * SW1 + r] = f2bf(v);
        return;
    }
    r -= SW1;
    if (r < SE2) { pack_std(eW2 + (long)l * 4096, eW2p + (long)l * SE2, 64, r); return; }
    r -= SE2;
    if (r < SN1) { pack_std(nW1 + (long)l * 24576, nW1p + (long)l * SN1, 128, r); return; }
    r -= SN1;
    if (r < SN2) { pack_std(nW2 + (long)l * 16384, nW2p + (long)l * SN2, 128, r); return; }
    r -= SN2;
    biasP[(long)l * 128 + r] = (r < 64) ? eb1[(long)l * 64 + r] : 0.0f;
}

// ---------------------------------------------------------------------------
// Generic bf16 MFMA GEMM: out[M,NOUT] = act(A[M,K] @ B + bias) (+resid)
// A bf16 row-major (optionally concat with fp32 A2 when SRC2K>0).
// B pre-packed in fragment order. Block=256 (4 waves), M-tile=64.
// ---------------------------------------------------------------------------
template<int K, int NOUT, int SRC2K, int ACT, int RES, int WF, int WB>
__global__ __launch_bounds__(256) void gemm_k(
    const unsigned short* __restrict__ A, const float* __restrict__ A2,
    const unsigned short* __restrict__ Bp, const float* __restrict__ bias,
    const float* __restrict__ resid, float* __restrict__ outF,
    unsigned short* __restrict__ outB, int M)
{
    constexpr int LDA = (SRC2K > 0) ? SRC2K : K;
    constexpr int STRIDE = K + 8;   // +8 bf16 pad: 2-way LDS bank alias only (free)
    __shared__ unsigned short As[64 * STRIDE];
    const int tid = threadIdx.x;
    const int m0 = blockIdx.x * 64;

    constexpr int CPR = K / 8;      // 16B chunks per row
    for (int t = tid; t < 64 * CPR; t += 256) {
        int rr = t / CPR, c = t % CPR;
        int row = m0 + rr;
        uintx4 val = {0, 0, 0, 0};
        if (row < M) {
            if (SRC2K == 0 || c * 8 < SRC2K) {
                val = *(const uintx4*)(A + (size_t)row * LDA + c * 8);
            } else {
                const float* s = A2 + (size_t)row * (K - SRC2K) + (c * 8 - SRC2K);
                unsigned short tmp[8];
                #pragma unroll
                for (int i = 0; i < 8; i++) tmp[i] = f2bf(s[i]);
                val = *(const uintx4*)tmp;
            }
        }
        *(uintx4*)(&As[rr * STRIDE + c * 8]) = val;
    }
    __syncthreads();

    const int wave = tid >> 6;
    const int lane = tid & 63;
    const int lrow = lane & 15;
    const int quad = lane >> 4;

    constexpr int NT = NOUT / 16;
    floatx4 acc[NT];
    #pragma unroll
    for (int i = 0; i < NT; i++) acc[i] = (floatx4){0, 0, 0, 0};

    const unsigned short* arow = &As[(wave * 16 + lrow) * STRIDE];
    #pragma unroll
    for (int kt = 0; kt < K / 32; kt++) {
        short8 afrag = *(const short8*)(arow + kt * 32 + quad * 8);
        int kb = kt * 4 + quad;
        #pragma unroll
        for (int nt = 0; nt < NT; nt++) {
            short8 bfrag = *(const short8*)(Bp + (size_t)(kb * NOUT + nt * 16 + lrow) * 8);
            acc[nt] = __builtin_amdgcn_mfma_f32_16x16x32_bf16(afrag, bfrag, acc[nt], 0, 0, 0);
        }
    }

    #pragma unroll
    for (int nt = 0; nt < NT; nt++) {
        int n = nt * 16 + lrow;
        float bv = bias[n];
        #pragma unroll
        for (int r = 0; r < 4; r++) {
            int row = m0 + wave * 16 + quad * 4 + r;
            if (row < M) {
                float v = acc[nt][r] + bv;
                if (ACT) v = silu_f(v);
                if (RES) v += resid[(size_t)row * NOUT + n];
                if (WF) outF[(size_t)row * NOUT + n] = v;
                if (WB) outB[(size_t)row * NOUT + n] = f2bf(v);
            }
        }
    }
}

// ---------------------------------------------------------------------------
// Edge kernel: per edge e: pre = P_top[row[e]] + P_bot[col[e]] (b1 folded
// into P_top); m = silu(pre); m2 = silu(m @ eW2 + b2); atomic agg[row[e]] += m2
// Block=256 (4 waves) handles 64 edges. K=64, NOUT=64.
// ---------------------------------------------------------------------------
__global__ __launch_bounds__(256) void edge_k(
    const int* __restrict__ erow, const int* __restrict__ ecol,
    const unsigned short* __restrict__ P,    // [N,128]: 0..63 top(+b1), 64..127 bot
    const unsigned short* __restrict__ Bp,   // eW2 frag order
    const float* __restrict__ b2, float* __restrict__ agg, int E)
{
    __shared__ unsigned short Ms[64 * 72];
    __shared__ int rid[64];
    const int tid = threadIdx.x;
    const int e0 = blockIdx.x * 64;

    {
        int el = tid >> 2;       // local edge
        int part = tid & 3;      // 16-feature chunk
        int e = e0 + el;
        if (e < E) {
            int rr = erow[e], cc = ecol[e];
            if (part == 0) rid[el] = rr;
            const uintx4* pt = (const uintx4*)(P + (size_t)rr * 128 + part * 16);
            const uintx4* pb = (const uintx4*)(P + (size_t)cc * 128 + 64 + part * 16);
            #pragma unroll
            for (int h = 0; h < 2; h++) {
                uintx4 a = pt[h], b = pb[h];
                const unsigned short* au = (const unsigned short*)&a;
                const unsigned short* bu = (const unsigned short*)&b;
                unsigned short o[8];
                #pragma unroll
                for (int i = 0; i < 8; i++) {
                    float x = bf2f(au[i]) + bf2f(bu[i]);
                    o[i] = f2bf(silu_f(x));
                }
                *(uintx4*)(&Ms[el * 72 + part * 16 + h * 8]) = *(const uintx4*)o;
            }
        } else if (part == 0) {
            rid[el] = -1;
        }
    }
    __syncthreads();

    const int wave = tid >> 6;
    const int lane = tid & 63;
    const int lrow = lane & 15;
    const int quad = lane >> 4;

    floatx4 acc[4];
    #pragma unroll
    for (int i = 0; i < 4; i++) acc[i] = (floatx4){0, 0, 0, 0};

    const unsigned short* arow = &Ms[(wave * 16 + lrow) * 72];
    #pragma unroll
    for (int kt = 0; kt < 2; kt++) {
        short8 afrag = *(const short8*)(arow + kt * 32 + quad * 8);
        int kb = kt * 4 + quad;
        #pragma unroll
        for (int nt = 0; nt < 4; nt++) {
            short8 bfrag = *(const short8*)(Bp + (size_t)(kb * 64 + nt * 16 + lrow) * 8);
            acc[nt] = __builtin_amdgcn_mfma_f32_16x16x32_bf16(afrag, bfrag, acc[nt], 0, 0, 0);
        }
    }

    #pragma unroll
    for (int nt = 0; nt < 4; nt++) {
        int n = nt * 16 + lrow;
        float bv = b2[n];
        #pragma unroll
        for (int r = 0; r < 4; r++) {
            int el = wave * 16 + quad * 4 + r;
            int rv = rid[el];
            if (rv >= 0) {
                float v = silu_f(acc[nt][r] + bv);
                atomicAdd(&agg[(size_t)rv * 64 + n], v);
            }
        }
    }
}

// ---------------------------------------------------------------------------
extern "C" void kernel_launch(void* const* d_in, const int* in_sizes, int n_in,
                              void* d_out, int out_size, void* d_ws, size_t ws_size,
                              hipStream_t stream) {
    const float* h0   = (const float*)d_in[0];
    const int*   edges= (const int*)d_in[1];
    const float* W_in = (const float*)d_in[2];
    const float* b_in = (const float*)d_in[3];
    const float* eW1  = (const float*)d_in[4];
    const float* eb1  = (const float*)d_in[5];
    const float* eW2  = (const float*)d_in[6];
    const float* eb2  = (const float*)d_in[7];
    const float* nW1  = (const float*)d_in[8];
    const float* nb1  = (const float*)d_in[9];
    const float* nW2  = (const float*)d_in[10];
    const float* nb2  = (const float*)d_in[11];
    const float* W_out= (const float*)d_in[12];
    const float* b_out= (const float*)d_in[13];
    float* out = (float*)d_out;

    const int E = in_sizes[1] / 2;      // 800000
    const int* erow = edges;
    const int* ecol = edges + E;

    char* ws = (char*)d_ws;
    // workspace layout (bytes, 256-aligned)
    unsigned short* hbf  = (unsigned short*)(ws + 0);            // 12,800,000
    float*          hbufF= (float*)(ws + 12800000);              // 25,600,000
    unsigned short* P    = (unsigned short*)(ws + 38400000);     // 12,800,000
    float*          agg  = (float*)(ws + 51200000);              // 12,800,000
    unsigned short* tbuf = (unsigned short*)(ws + 64000000);     // 12,800,000
    unsigned short* h0bf = (unsigned short*)(ws + 76800000);     //  6,400,000
    float*          biasP= (float*)(ws + 83200000);              //  2,048
    unsigned short* Winp = (unsigned short*)(ws + 83202048);     // 16,384
    unsigned short* Woutp= (unsigned short*)(ws + 83218432);     // 16,384
    unsigned short* W1p  = (unsigned short*)(ws + 83234816);     // 131,072
    unsigned short* eW2p = (unsigned short*)(ws + 83365888);     // 32,768
    unsigned short* nW1p = (unsigned short*)(ws + 83398656);     // 196,608
    unsigned short* nW2p = (unsigned short*)(ws + 83595264);     // 131,072

    const int gemm_grid = (N_NODES + 63) / 64;    // 782
    const int edge_grid = (E + 63) / 64;          // 12500
    const int pack_grid = (int)((PACK_TOTAL + 255) / 256);

    pack_kernel<<<pack_grid, 256, 0, stream>>>(h0, W_in, W_out, eW1, eb1, eW2,
                                               nW1, nW2, h0bf, Winp, Woutp, W1p,
                                               eW2p, nW1p, nW2p, biasP);

    // h = h0 @ W_in + b_in  -> hbufF (fp32) + hbf (bf16)
    gemm_k<64, 128, 0, 0, 0, 1, 1><<<gemm_grid, 256, 0, stream>>>(
        h0bf, nullptr, Winp, b_in, nullptr, hbufF, hbf, N_NODES);

    for (int l = 0; l < 4; l++) {
        hipMemsetAsync(agg, 0, (size_t)N_NODES * 64 * 4, stream);
        // P = hbf @ W1' + (eb1|0)   [N,128] bf16
        gemm_k<128, 128, 0, 0, 0, 0, 1><<<gemm_grid, 256, 0, stream>>>(
            hbf, nullptr, W1p + (size_t)l * SW1, biasP + (size_t)l * 128,
            nullptr, nullptr, P, N_NODES);
        // edge phase -> atomic agg
        edge_k<<<edge_grid, 256, 0, stream>>>(
            erow, ecol, P, eW2p + (size_t)l * SE2, eb2 + (size_t)l * 64, agg, E);
        // t = silu([hbf | agg] @ nW1 + nb1)
        gemm_k<192, 128, 128, 1, 0, 0, 1><<<gemm_grid, 256, 0, stream>>>(
            hbf, agg, nW1p + (size_t)l * SN1, nb1 + (size_t)l * 128,
            nullptr, nullptr, tbuf, N_NODES);
        // h = h + (t @ nW2 + nb2)  -> hbufF (fp32, in-place) + hbf
        gemm_k<128, 128, 0, 0, 1, 1, 1><<<gemm_grid, 256, 0, stream>>>(
            tbuf, nullptr, nW2p + (size_t)l * SN2, nb2 + (size_t)l * 128,
            hbufF, hbufF, hbf, N_NODES);
    }

    // out = hbf @ W_out + b_out
    gemm_k<128, 64, 0, 0, 0, 1, 0><<<gemm_grid, 256, 0, stream>>>(
        hbf, nullptr, Woutp, b_out, nullptr, out, nullptr, N_NODES);
}

// Round 2
// 682.558 us; speedup vs baseline: 1.4716x; 1.4716x over previous
//
#include <hip/hip_runtime.h>
#include <hip/hip_bf16.h>
#include <cstdint>
#include <cstddef>

#define N_NODES 50000
#define N_EDGES 800000

typedef __attribute__((ext_vector_type(8))) short short8;
typedef __attribute__((ext_vector_type(4))) float floatx4;
typedef __attribute__((ext_vector_type(4))) unsigned int uintx4;

__device__ inline float bf2f(unsigned short u) {
    union { unsigned int i; float f; } v; v.i = ((unsigned int)u) << 16; return v.f;
}
__device__ inline unsigned short f2bf(float f) {
    union { float f; unsigned int i; } v; v.f = f;
    unsigned int u = v.i;
    return (unsigned short)((u + 0x7FFFu + ((u >> 16) & 1u)) >> 16);
}
__device__ inline float silu_f(float x) {
    return x / (1.0f + __expf(-x));
}

// ---------------------------------------------------------------------------
// Pack kernel: fp32->bf16 conversions + weight rearrangement into MFMA
// B-fragment order: Bp[(kb*NOUT + n)*8 + i] = B[(kb*8+i)*NOUT + n]
// ---------------------------------------------------------------------------
__device__ inline void pack_std(const float* __restrict__ src,
                                unsigned short* __restrict__ dst,
                                int NOUT, long j) {
    int i = (int)(j & 7);
    long rest = j >> 3;
    int n = (int)(rest % NOUT);
    int kb = (int)(rest / NOUT);
    dst[j] = f2bf(src[(long)(kb * 8 + i) * NOUT + n]);
}

#define NH0   (N_NODES * 64L)
#define SW_IN 8192L
#define SW_OUT 8192L
#define SW1   16384L
#define SE2   4096L
#define SN1   24576L
#define SN2   16384L
#define SB    128L
#define PERL  (SW1 + SE2 + SN1 + SN2 + SB)
#define PACK_TOTAL (NH0 + SW_IN + SW_OUT + 4 * PERL)

__global__ __launch_bounds__(256) void pack_kernel(
    const float* __restrict__ h0, const float* __restrict__ W_in,
    const float* __restrict__ W_out, const float* __restrict__ eW1,
    const float* __restrict__ eb1, const float* __restrict__ eW2,
    const float* __restrict__ nW1, const float* __restrict__ nW2,
    unsigned short* __restrict__ h0bf, unsigned short* __restrict__ Winp,
    unsigned short* __restrict__ Woutp, unsigned short* __restrict__ W1p,
    unsigned short* __restrict__ eW2p, unsigned short* __restrict__ nW1p,
    unsigned short* __restrict__ nW2p, float* __restrict__ biasP)
{
    long idx = (long)blockIdx.x * 256 + threadIdx.x;
    if (idx >= PACK_TOTAL) return;
    long j = idx;
    if (j < NH0) { h0bf[j] = f2bf(h0[j]); return; }
    j -= NH0;
    if (j < SW_IN) { pack_std(W_in, Winp, 128, j); return; }
    j -= SW_IN;
    if (j < SW_OUT) { pack_std(W_out, Woutp, 64, j); return; }
    j -= SW_OUT;
    int l = (int)(j / PERL);
    long r = j % PERL;
    if (r < SW1) {
        int i = (int)(r & 7);
        int n = (int)((r >> 3) & 127);
        int kb = (int)(r >> 10);
        int k = kb * 8 + i;
        const float* w = eW1 + (long)l * 256 * 64;
        float v = (n < 64) ? w[(long)k * 64 + n] : w[(long)(128 + k) * 64 + (n - 64)];
        W1p[(long)l * SW1 + r] = f2bf(v);
        return;
    }
    r -= SW1;
    if (r < SE2) { pack_std(eW2 + (long)l * 4096, eW2p + (long)l * SE2, 64, r); return; }
    r -= SE2;
    if (r < SN1) { pack_std(nW1 + (long)l * 24576, nW1p + (long)l * SN1, 128, r); return; }
    r -= SN1;
    if (r < SN2) { pack_std(nW2 + (long)l * 16384, nW2p + (long)l * SN2, 128, r); return; }
    r -= SN2;
    biasP[(long)l * 128 + r] = (r < 64) ? eb1[(long)l * 64 + r] : 0.0f;
}

// ---------------------------------------------------------------------------
// Generic bf16 MFMA GEMM (same as round 1)
// ---------------------------------------------------------------------------
template<int K, int NOUT, int SRC2K, int ACT, int RES, int WF, int WB>
__global__ __launch_bounds__(256) void gemm_k(
    const unsigned short* __restrict__ A, const float* __restrict__ A2,
    const unsigned short* __restrict__ Bp, const float* __restrict__ bias,
    const float* __restrict__ resid, float* __restrict__ outF,
    unsigned short* __restrict__ outB, int M)
{
    constexpr int LDA = (SRC2K > 0) ? SRC2K : K;
    constexpr int STRIDE = K + 8;
    __shared__ unsigned short As[64 * STRIDE];
    const int tid = threadIdx.x;
    const int m0 = blockIdx.x * 64;

    constexpr int CPR = K / 8;
    for (int t = tid; t < 64 * CPR; t += 256) {
        int rr = t / CPR, c = t % CPR;
        int row = m0 + rr;
        uintx4 val = {0, 0, 0, 0};
        if (row < M) {
            if (SRC2K == 0 || c * 8 < SRC2K) {
                val = *(const uintx4*)(A + (size_t)row * LDA + c * 8);
            } else {
                const float* s = A2 + (size_t)row * (K - SRC2K) + (c * 8 - SRC2K);
                unsigned short tmp[8];
                #pragma unroll
                for (int i = 0; i < 8; i++) tmp[i] = f2bf(s[i]);
                val = *(const uintx4*)tmp;
            }
        }
        *(uintx4*)(&As[rr * STRIDE + c * 8]) = val;
    }
    __syncthreads();

    const int wave = tid >> 6;
    const int lane = tid & 63;
    const int lrow = lane & 15;
    const int quad = lane >> 4;

    constexpr int NT = NOUT / 16;
    floatx4 acc[NT];
    #pragma unroll
    for (int i = 0; i < NT; i++) acc[i] = (floatx4){0, 0, 0, 0};

    const unsigned short* arow = &As[(wave * 16 + lrow) * STRIDE];
    #pragma unroll
    for (int kt = 0; kt < K / 32; kt++) {
        short8 afrag = *(const short8*)(arow + kt * 32 + quad * 8);
        int kb = kt * 4 + quad;
        #pragma unroll
        for (int nt = 0; nt < NT; nt++) {
            short8 bfrag = *(const short8*)(Bp + (size_t)(kb * NOUT + nt * 16 + lrow) * 8);
            acc[nt] = __builtin_amdgcn_mfma_f32_16x16x32_bf16(afrag, bfrag, acc[nt], 0, 0, 0);
        }
    }

    #pragma unroll
    for (int nt = 0; nt < NT; nt++) {
        int n = nt * 16 + lrow;
        float bv = bias[n];
        #pragma unroll
        for (int r = 0; r < 4; r++) {
            int row = m0 + wave * 16 + quad * 4 + r;
            if (row < M) {
                float v = acc[nt][r] + bv;
                if (ACT) v = silu_f(v);
                if (RES) v += resid[(size_t)row * NOUT + n];
                if (WF) outF[(size_t)row * NOUT + n] = v;
                if (WB) outB[(size_t)row * NOUT + n] = f2bf(v);
            }
        }
    }
}

// ---------------------------------------------------------------------------
// CSR build kernels (once per launch; edges static within a call)
// ---------------------------------------------------------------------------
__global__ __launch_bounds__(256) void hist_k(const int* __restrict__ erow,
                                              int* __restrict__ counts, int E) {
    int e = blockIdx.x * 256 + threadIdx.x;
    if (e < E) atomicAdd(&counts[erow[e]], 1);
}

// per-block exclusive scan (1024/block); writes block sums
__global__ __launch_bounds__(1024) void scan1_k(const int* __restrict__ counts,
                                                int* __restrict__ cursor,
                                                int* __restrict__ bsum, int n) {
    __shared__ int buf[1024];
    int i = blockIdx.x * 1024 + threadIdx.x;
    int v = (i < n) ? counts[i] : 0;
    buf[threadIdx.x] = v;
    __syncthreads();
    #pragma unroll
    for (int off = 1; off < 1024; off <<= 1) {
        int t = (threadIdx.x >= off) ? buf[threadIdx.x - off] : 0;
        __syncthreads();
        buf[threadIdx.x] += t;
        __syncthreads();
    }
    if (i < n) cursor[i] = buf[threadIdx.x] - v;   // exclusive within block
    if (threadIdx.x == 1023) bsum[blockIdx.x] = buf[1023];
}

// exclusive scan of block sums (single block, <=64 blocks)
__global__ __launch_bounds__(64) void scan2_k(int* __restrict__ bsum, int nb) {
    __shared__ int b[64];
    int tid = threadIdx.x;
    int v = (tid < nb) ? bsum[tid] : 0;
    b[tid] = v;
    __syncthreads();
    #pragma unroll
    for (int off = 1; off < 64; off <<= 1) {
        int t = (tid >= off) ? b[tid - off] : 0;
        __syncthreads();
        b[tid] += t;
        __syncthreads();
    }
    if (tid < nb) bsum[tid] = b[tid] - v;          // exclusive
}

__global__ __launch_bounds__(1024) void scan3_k(int* __restrict__ cursor,
                                                const int* __restrict__ bsum, int n) {
    int i = blockIdx.x * 1024 + threadIdx.x;
    if (i < n) cursor[i] += bsum[blockIdx.x];
}

__global__ __launch_bounds__(256) void scatter_k(const int* __restrict__ erow,
                                                 const int* __restrict__ ecol,
                                                 int* __restrict__ cursor,
                                                 int* __restrict__ rowS,
                                                 int* __restrict__ colS, int E) {
    int e = blockIdx.x * 256 + threadIdx.x;
    if (e < E) {
        int r = erow[e];
        int s = atomicAdd(&cursor[r], 1);
        rowS[s] = r;
        colS[s] = ecol[e];
    }
}

// ---------------------------------------------------------------------------
// Fused edge + segmented-aggregate kernel over CSR-sorted edges.
// Block = 256 threads = 64 edge slots. Rows sorted ascending ->
// interior segments store directly; boundary segments atomicAdd.
// ---------------------------------------------------------------------------
__global__ __launch_bounds__(256) void edge_fused_k(
    const int* __restrict__ rowS, const int* __restrict__ colS,
    const unsigned short* __restrict__ P,    // [N,128]: 0..63 top(+b1), 64..127 bot
    const unsigned short* __restrict__ Bp,   // eW2 frag order
    const float* __restrict__ b2, float* __restrict__ agg, int E)
{
    __shared__ unsigned short Ms[64 * 72];
    __shared__ float M2s[64 * 64];
    __shared__ int ridS[64];
    __shared__ short segStartS[66];
    __shared__ int nsegS;
    const int tid = threadIdx.x;
    const int e0 = blockIdx.x * 64;

    // stage 1: gather endpoints, silu(Ptop[row]+Pbot[col]) -> Ms (bf16)
    {
        int el = tid >> 2;
        int part = tid & 3;
        int s = e0 + el;
        if (s < E) {
            int rr = rowS[s], cc = colS[s];
            if (part == 0) ridS[el] = rr;
            const uintx4* pt = (const uintx4*)(P + (size_t)rr * 128 + part * 16);
            const uintx4* pb = (const uintx4*)(P + (size_t)cc * 128 + 64 + part * 16);
            #pragma unroll
            for (int h = 0; h < 2; h++) {
                uintx4 a = pt[h], b = pb[h];
                const unsigned short* au = (const unsigned short*)&a;
                const unsigned short* bu = (const unsigned short*)&b;
                unsigned short o[8];
                #pragma unroll
                for (int i = 0; i < 8; i++) {
                    float x = bf2f(au[i]) + bf2f(bu[i]);
                    o[i] = f2bf(silu_f(x));
                }
                *(uintx4*)(&Ms[el * 72 + part * 16 + h * 8]) = *(const uintx4*)o;
            }
        } else if (part == 0) {
            ridS[el] = -1;
        }
    }
    __syncthreads();

    // stage 2: m2 = Ms @ eW2 via MFMA
    const int wave = tid >> 6;
    const int lane = tid & 63;
    const int lrow = lane & 15;
    const int quad = lane >> 4;

    floatx4 acc[4];
    #pragma unroll
    for (int i = 0; i < 4; i++) acc[i] = (floatx4){0, 0, 0, 0};

    const unsigned short* arow = &Ms[(wave * 16 + lrow) * 72];
    #pragma unroll
    for (int kt = 0; kt < 2; kt++) {
        short8 afrag = *(const short8*)(arow + kt * 32 + quad * 8);
        int kb = kt * 4 + quad;
        #pragma unroll
        for (int nt = 0; nt < 4; nt++) {
            short8 bfrag = *(const short8*)(Bp + (size_t)(kb * 64 + nt * 16 + lrow) * 8);
            acc[nt] = __builtin_amdgcn_mfma_f32_16x16x32_bf16(afrag, bfrag, acc[nt], 0, 0, 0);
        }
    }

    // stage 3: silu(m2 + b2) -> M2s (fp32), C-layout scatter into LDS
    #pragma unroll
    for (int nt = 0; nt < 4; nt++) {
        int n = nt * 16 + lrow;
        float bv = b2[n];
        #pragma unroll
        for (int r = 0; r < 4; r++) {
            int el = wave * 16 + quad * 4 + r;
            M2s[el * 64 + n] = silu_f(acc[nt][r] + bv);
        }
    }

    // segment detection (wave 0 only; ridS stable since first barrier)
    if (tid < 64) {
        bool st = (ridS[tid] >= 0) && (tid == 0 || ridS[tid] != ridS[tid - 1]);
        unsigned long long m = __ballot(st);
        if (st) {
            int pos = __popcll(m & ((1ull << tid) - 1));
            segStartS[pos] = (short)tid;
        }
        if (tid == 0) {
            int ns = __popcll(m);
            nsegS = ns;
            int nvalid = E - e0;
            if (nvalid > 64) nvalid = 64;
            segStartS[ns] = (short)nvalid;
        }
    }
    __syncthreads();

    // stage 4: segmented reduce; wave g handles segments g, g+4, ...
    // lane = feature. Interior segments are block-exclusive -> plain store.
    {
        int f = tid & 63;
        int g = tid >> 6;
        int ns = nsegS;
        for (int j = g; j < ns; j += 4) {
            int a = segStartS[j], b = segStartS[j + 1];
            float s = 0.0f;
            for (int el = a; el < b; el++) s += M2s[el * 64 + f];
            int rv = ridS[a];
            if (j == 0 || j == ns - 1)
                atomicAdd(&agg[(size_t)rv * 64 + f], s);
            else
                agg[(size_t)rv * 64 + f] = s;
        }
    }
}

// ---------------------------------------------------------------------------
extern "C" void kernel_launch(void* const* d_in, const int* in_sizes, int n_in,
                              void* d_out, int out_size, void* d_ws, size_t ws_size,
                              hipStream_t stream) {
    const float* h0   = (const float*)d_in[0];
    const int*   edges= (const int*)d_in[1];
    const float* W_in = (const float*)d_in[2];
    const float* b_in = (const float*)d_in[3];
    const float* eW1  = (const float*)d_in[4];
    const float* eb1  = (const float*)d_in[5];
    const float* eW2  = (const float*)d_in[6];
    const float* eb2  = (const float*)d_in[7];
    const float* nW1  = (const float*)d_in[8];
    const float* nb1  = (const float*)d_in[9];
    const float* nW2  = (const float*)d_in[10];
    const float* nb2  = (const float*)d_in[11];
    const float* W_out= (const float*)d_in[12];
    const float* b_out= (const float*)d_in[13];
    float* out = (float*)d_out;

    const int E = in_sizes[1] / 2;      // 800000
    const int* erow = edges;
    const int* ecol = edges + E;

    char* ws = (char*)d_ws;
    unsigned short* hbf  = (unsigned short*)(ws + 0);            // 12,800,000
    float*          hbufF= (float*)(ws + 12800000);              // 25,600,000
    unsigned short* P    = (unsigned short*)(ws + 38400000);     // 12,800,000
    float*          agg  = (float*)(ws + 51200000);              // 12,800,000
    unsigned short* tbuf = (unsigned short*)(ws + 64000000);     // 12,800,000
    // h0bf (start only) aliases rowS/colS (used after gemm_in)
    unsigned short* h0bf = (unsigned short*)(ws + 76800000);     //  6,400,000
    int*            rowS = (int*)(ws + 76800000);                //  3,200,000
    int*            colS = (int*)(ws + 80000000);                //  3,200,000
    float*          biasP= (float*)(ws + 83200000);              //  2,048
    unsigned short* Winp = (unsigned short*)(ws + 83202048);     // 16,384
    unsigned short* Woutp= (unsigned short*)(ws + 83218432);     // 16,384
    unsigned short* W1p  = (unsigned short*)(ws + 83234816);     // 131,072
    unsigned short* eW2p = (unsigned short*)(ws + 83365888);     // 32,768
    unsigned short* nW1p = (unsigned short*)(ws + 83398656);     // 196,608
    unsigned short* nW2p = (unsigned short*)(ws + 83595264);     // 131,072
    int*            counts=(int*)(ws + 83726336);                // 200,000
    int*            cursor=(int*)(ws + 83926336);                // 200,000
    int*            bsum = (int*)(ws + 84126336);                // 256

    const int gemm_grid = (N_NODES + 63) / 64;    // 782
    const int edge_grid = (E + 63) / 64;          // 12500
    const int pack_grid = (int)((PACK_TOTAL + 255) / 256);
    const int nb = (N_NODES + 1023) / 1024;       // 49

    pack_kernel<<<pack_grid, 256, 0, stream>>>(h0, W_in, W_out, eW1, eb1, eW2,
                                               nW1, nW2, h0bf, Winp, Woutp, W1p,
                                               eW2p, nW1p, nW2p, biasP);

    // h = h0 @ W_in + b_in  (reads h0bf; must precede scatter which reuses region)
    gemm_k<64, 128, 0, 0, 0, 1, 1><<<gemm_grid, 256, 0, stream>>>(
        h0bf, nullptr, Winp, b_in, nullptr, hbufF, hbf, N_NODES);

    // CSR build
    hipMemsetAsync(counts, 0, (size_t)N_NODES * 4, stream);
    hist_k<<<(E + 255) / 256, 256, 0, stream>>>(erow, counts, E);
    scan1_k<<<nb, 1024, 0, stream>>>(counts, cursor, bsum, N_NODES);
    scan2_k<<<1, 64, 0, stream>>>(bsum, nb);
    scan3_k<<<nb, 1024, 0, stream>>>(cursor, bsum, N_NODES);
    scatter_k<<<(E + 255) / 256, 256, 0, stream>>>(erow, ecol, cursor, rowS, colS, E);

    for (int l = 0; l < 4; l++) {
        hipMemsetAsync(agg, 0, (size_t)N_NODES * 64 * 4, stream);
        // P = hbf @ W1' + (eb1|0)   [N,128] bf16
        gemm_k<128, 128, 0, 0, 0, 0, 1><<<gemm_grid, 256, 0, stream>>>(
            hbf, nullptr, W1p + (size_t)l * SW1, biasP + (size_t)l * 128,
            nullptr, nullptr, P, N_NODES);
        // fused edge compute + segmented aggregate
        edge_fused_k<<<edge_grid, 256, 0, stream>>>(
            rowS, colS, P, eW2p + (size_t)l * SE2, eb2 + (size_t)l * 64, agg, E);
        // t = silu([hbf | agg] @ nW1 + nb1)
        gemm_k<192, 128, 128, 1, 0, 0, 1><<<gemm_grid, 256, 0, stream>>>(
            hbf, agg, nW1p + (size_t)l * SN1, nb1 + (size_t)l * 128,
            nullptr, nullptr, tbuf, N_NODES);
        // h = h + (t @ nW2 + nb2)
        gemm_k<128, 128, 0, 0, 1, 1, 1><<<gemm_grid, 256, 0, stream>>>(
            tbuf, nullptr, nW2p + (size_t)l * SN2, nb2 + (size_t)l * 128,
            hbufF, hbufF, hbf, N_NODES);
    }

    // out = hbf @ W_out + b_out
    gemm_k<128, 64, 0, 0, 0, 1, 0><<<gemm_grid, 256, 0, stream>>>(
        hbf, nullptr, Woutp, b_out, nullptr, out, nullptr, N_NODES);
}

// Round 3
// 643.706 us; speedup vs baseline: 1.5604x; 1.0604x over previous
//
#include <hip/hip_runtime.h>
#include <hip/hip_bf16.h>
#include <cstdint>
#include <cstddef>

#define N_NODES 50000
#define N_EDGES 800000

typedef __attribute__((ext_vector_type(8))) short short8;
typedef __attribute__((ext_vector_type(4))) float floatx4;
typedef __attribute__((ext_vector_type(4))) unsigned int uintx4;

__device__ inline float bf2f(unsigned short u) {
    union { unsigned int i; float f; } v; v.i = ((unsigned int)u) << 16; return v.f;
}
__device__ inline unsigned short f2bf(float f) {
    union { float f; unsigned int i; } v; v.f = f;
    unsigned int u = v.i;
    return (unsigned short)((u + 0x7FFFu + ((u >> 16) & 1u)) >> 16);
}
// silu via v_rcp_f32 (1 ulp) instead of IEEE divide (~10 VALU ops saved/call)
__device__ inline float silu_f(float x) {
    float e = __expf(-x);
    return x * __builtin_amdgcn_rcpf(1.0f + e);
}

// ---------------------------------------------------------------------------
// Pack kernel: fp32->bf16 conversions + weight rearrangement into MFMA
// B-fragment order: Bp[(kb*NOUT + n)*8 + i] = B[(kb*8+i)*NOUT + n]
// ---------------------------------------------------------------------------
__device__ inline void pack_std(const float* __restrict__ src,
                                unsigned short* __restrict__ dst,
                                int NOUT, long j) {
    int i = (int)(j & 7);
    long rest = j >> 3;
    int n = (int)(rest % NOUT);
    int kb = (int)(rest / NOUT);
    dst[j] = f2bf(src[(long)(kb * 8 + i) * NOUT + n]);
}

#define NH0   (N_NODES * 64L)
#define SW_IN 8192L
#define SW_OUT 8192L
#define SW1   16384L
#define SE2   4096L
#define SN1   24576L
#define SN2   16384L
#define SB    128L
#define PERL  (SW1 + SE2 + SN1 + SN2 + SB)
#define PACK_TOTAL (NH0 + SW_IN + SW_OUT + 4 * PERL)

__global__ __launch_bounds__(256) void pack_kernel(
    const float* __restrict__ h0, const float* __restrict__ W_in,
    const float* __restrict__ W_out, const float* __restrict__ eW1,
    const float* __restrict__ eb1, const float* __restrict__ eW2,
    const float* __restrict__ nW1, const float* __restrict__ nW2,
    unsigned short* __restrict__ h0bf, unsigned short* __restrict__ Winp,
    unsigned short* __restrict__ Woutp, unsigned short* __restrict__ W1p,
    unsigned short* __restrict__ eW2p, unsigned short* __restrict__ nW1p,
    unsigned short* __restrict__ nW2p, float* __restrict__ biasP)
{
    long idx = (long)blockIdx.x * 256 + threadIdx.x;
    if (idx >= PACK_TOTAL) return;
    long j = idx;
    if (j < NH0) { h0bf[j] = f2bf(h0[j]); return; }
    j -= NH0;
    if (j < SW_IN) { pack_std(W_in, Winp, 128, j); return; }
    j -= SW_IN;
    if (j < SW_OUT) { pack_std(W_out, Woutp, 64, j); return; }
    j -= SW_OUT;
    int l = (int)(j / PERL);
    long r = j % PERL;
    if (r < SW1) {
        int i = (int)(r & 7);
        int n = (int)((r >> 3) & 127);
        int kb = (int)(r >> 10);
        int k = kb * 8 + i;
        const float* w = eW1 + (long)l * 256 * 64;
        float v = (n < 64) ? w[(long)k * 64 + n] : w[(long)(128 + k) * 64 + (n - 64)];
        W1p[(long)l * SW1 + r] = f2bf(v);
        return;
    }
    r -= SW1;
    if (r < SE2) { pack_std(eW2 + (long)l * 4096, eW2p + (long)l * SE2, 64, r); return; }
    r -= SE2;
    if (r < SN1) { pack_std(nW1 + (long)l * 24576, nW1p + (long)l * SN1, 128, r); return; }
    r -= SN1;
    if (r < SN2) { pack_std(nW2 + (long)l * 16384, nW2p + (long)l * SN2, 128, r); return; }
    r -= SN2;
    biasP[(long)l * 128 + r] = (r < 64) ? eb1[(long)l * 64 + r] : 0.0f;
}

// ---------------------------------------------------------------------------
// CSR build kernels (once per launch)
// ---------------------------------------------------------------------------
__global__ __launch_bounds__(256) void hist_k(const int* __restrict__ erow,
                                              int* __restrict__ counts, int E) {
    int e = blockIdx.x * 256 + threadIdx.x;
    if (e < E) atomicAdd(&counts[erow[e]], 1);
}

__global__ __launch_bounds__(1024) void scan1_k(const int* __restrict__ counts,
                                                int* __restrict__ cursor,
                                                int* __restrict__ bsum, int n) {
    __shared__ int buf[1024];
    int i = blockIdx.x * 1024 + threadIdx.x;
    int v = (i < n) ? counts[i] : 0;
    buf[threadIdx.x] = v;
    __syncthreads();
    #pragma unroll
    for (int off = 1; off < 1024; off <<= 1) {
        int t = (threadIdx.x >= off) ? buf[threadIdx.x - off] : 0;
        __syncthreads();
        buf[threadIdx.x] += t;
        __syncthreads();
    }
    if (i < n) cursor[i] = buf[threadIdx.x] - v;
    if (threadIdx.x == 1023) bsum[blockIdx.x] = buf[1023];
}

__global__ __launch_bounds__(64) void scan2_k(int* __restrict__ bsum, int nb) {
    __shared__ int b[64];
    int tid = threadIdx.x;
    int v = (tid < nb) ? bsum[tid] : 0;
    b[tid] = v;
    __syncthreads();
    #pragma unroll
    for (int off = 1; off < 64; off <<= 1) {
        int t = (tid >= off) ? b[tid - off] : 0;
        __syncthreads();
        b[tid] += t;
        __syncthreads();
    }
    if (tid < nb) bsum[tid] = b[tid] - v;
}

__global__ __launch_bounds__(1024) void scan3_k(int* __restrict__ cursor,
                                                const int* __restrict__ bsum, int n) {
    int i = blockIdx.x * 1024 + threadIdx.x;
    if (i < n) cursor[i] += bsum[blockIdx.x];
}

__global__ __launch_bounds__(256) void scatter_k(const int* __restrict__ erow,
                                                 const int* __restrict__ ecol,
                                                 int* __restrict__ cursor,
                                                 int* __restrict__ rowS,
                                                 int* __restrict__ colS, int E) {
    int e = blockIdx.x * 256 + threadIdx.x;
    if (e < E) {
        int r = erow[e];
        int s = atomicAdd(&cursor[r], 1);
        rowS[s] = r;
        colS[s] = ecol[e];
    }
}

// ---------------------------------------------------------------------------
// Fused edge + segmented-aggregate kernel over CSR-sorted edges.
// ---------------------------------------------------------------------------
__global__ __launch_bounds__(256) void edge_fused_k(
    const int* __restrict__ rowS, const int* __restrict__ colS,
    const unsigned short* __restrict__ P,    // [N,128]: 0..63 top(+b1), 64..127 bot
    const unsigned short* __restrict__ Bp,   // eW2 frag order
    const float* __restrict__ b2, float* __restrict__ agg, int E)
{
    __shared__ unsigned short Ms[64 * 72];
    __shared__ float M2s[64 * 68];           // stride 68: kills 4-way write conflict
    __shared__ int ridS[64];
    __shared__ short segStartS[66];
    __shared__ int nsegS;
    const int tid = threadIdx.x;
    const int e0 = blockIdx.x * 64;

    // stage 1: gather endpoints, silu(Ptop[row]+Pbot[col]) -> Ms (bf16)
    {
        int el = tid >> 2;
        int part = tid & 3;
        int s = e0 + el;
        if (s < E) {
            int rr = rowS[s], cc = colS[s];
            if (part == 0) ridS[el] = rr;
            const uintx4* pt = (const uintx4*)(P + (size_t)rr * 128 + part * 16);
            const uintx4* pb = (const uintx4*)(P + (size_t)cc * 128 + 64 + part * 16);
            #pragma unroll
            for (int h = 0; h < 2; h++) {
                uintx4 a = pt[h], b = pb[h];
                const unsigned short* au = (const unsigned short*)&a;
                const unsigned short* bu = (const unsigned short*)&b;
                unsigned short o[8];
                #pragma unroll
                for (int i = 0; i < 8; i++) {
                    float x = bf2f(au[i]) + bf2f(bu[i]);
                    o[i] = f2bf(silu_f(x));
                }
                *(uintx4*)(&Ms[el * 72 + part * 16 + h * 8]) = *(const uintx4*)o;
            }
        } else if (part == 0) {
            ridS[el] = -1;
        }
    }
    __syncthreads();

    // stage 2: m2 = Ms @ eW2 via MFMA
    const int wave = tid >> 6;
    const int lane = tid & 63;
    const int lrow = lane & 15;
    const int quad = lane >> 4;

    floatx4 acc[4];
    #pragma unroll
    for (int i = 0; i < 4; i++) acc[i] = (floatx4){0, 0, 0, 0};

    const unsigned short* arow = &Ms[(wave * 16 + lrow) * 72];
    #pragma unroll
    for (int kt = 0; kt < 2; kt++) {
        short8 afrag = *(const short8*)(arow + kt * 32 + quad * 8);
        int kb = kt * 4 + quad;
        #pragma unroll
        for (int nt = 0; nt < 4; nt++) {
            short8 bfrag = *(const short8*)(Bp + (size_t)(kb * 64 + nt * 16 + lrow) * 8);
            acc[nt] = __builtin_amdgcn_mfma_f32_16x16x32_bf16(afrag, bfrag, acc[nt], 0, 0, 0);
        }
    }

    // stage 3: silu(m2 + b2) -> M2s (fp32)
    #pragma unroll
    for (int nt = 0; nt < 4; nt++) {
        int n = nt * 16 + lrow;
        float bv = b2[n];
        #pragma unroll
        for (int r = 0; r < 4; r++) {
            int el = wave * 16 + quad * 4 + r;
            M2s[el * 68 + n] = silu_f(acc[nt][r] + bv);
        }
    }

    // segment detection (wave 0)
    if (tid < 64) {
        bool st = (ridS[tid] >= 0) && (tid == 0 || ridS[tid] != ridS[tid - 1]);
        unsigned long long m = __ballot(st);
        if (st) {
            int pos = __popcll(m & ((1ull << tid) - 1));
            segStartS[pos] = (short)tid;
        }
        if (tid == 0) {
            int ns = __popcll(m);
            nsegS = ns;
            int nvalid = E - e0;
            if (nvalid > 64) nvalid = 64;
            segStartS[ns] = (short)nvalid;
        }
    }
    __syncthreads();

    // stage 4: segmented reduce; interior segments plain-store, edges atomic
    {
        int f = tid & 63;
        int g = tid >> 6;
        int ns = nsegS;
        for (int j = g; j < ns; j += 4) {
            int a = segStartS[j], b = segStartS[j + 1];
            float s = 0.0f;
            for (int el = a; el < b; el++) s += M2s[el * 68 + f];
            int rv = ridS[a];
            if (j == 0 || j == ns - 1)
                atomicAdd(&agg[(size_t)rv * 64 + f], s);
            else
                agg[(size_t)rv * 64 + f] = s;
        }
    }
}

// ---------------------------------------------------------------------------
// Fused node-side chain (per layer, per 64-row tile):
//   t     = silu([h | agg] @ nW1 + nb1)      (K=192 -> 128)
//   h_new = h + t @ nW2 + nb2                (K=128 -> 128, fp32 resid)
//   FINAL=0: P = h_new @ W1'[l+1] + biasP    (K=128 -> 128, bf16)
//   FINAL=1: out = h_new @ W_out + b_out     (K=128 -> 64, fp32)
// Intermediates live in one reused LDS buffer.
// ---------------------------------------------------------------------------
template<int FINAL>
__global__ __launch_bounds__(256) void node_fused_k(
    const unsigned short* __restrict__ hbf, const float* __restrict__ agg,
    const unsigned short* __restrict__ W1, const float* __restrict__ b1,
    const unsigned short* __restrict__ W2, const float* __restrict__ b2,
    const unsigned short* __restrict__ B3, const float* __restrict__ bias3,
    float* __restrict__ hF, unsigned short* __restrict__ hB,
    unsigned short* __restrict__ Pout, float* __restrict__ outF, int M)
{
    __shared__ unsigned short As[64 * 200];  // phase A: stride 200; then reused
    const int tid = threadIdx.x;
    const int m0 = blockIdx.x * 64;

    // ---- phase A staging: [h(128 bf16) | agg(64 fp32->bf16)] ----
    for (int t = tid; t < 64 * 24; t += 256) {
        int rr = t / 24, c = t % 24;
        int row = m0 + rr;
        uintx4 val = {0, 0, 0, 0};
        if (row < M) {
            if (c < 16) {
                val = *(const uintx4*)(hbf + (size_t)row * 128 + c * 8);
            } else {
                const float* s = agg + (size_t)row * 64 + (c - 16) * 8;
                unsigned short tmp[8];
                #pragma unroll
                for (int i = 0; i < 8; i++) tmp[i] = f2bf(s[i]);
                val = *(const uintx4*)tmp;
            }
        }
        *(uintx4*)(&As[rr * 200 + c * 8]) = val;
    }
    __syncthreads();

    const int wave = tid >> 6;
    const int lane = tid & 63;
    const int lrow = lane & 15;
    const int quad = lane >> 4;

    // ---- phase A MFMA: K=192, NOUT=128 ----
    floatx4 acc[8];
    #pragma unroll
    for (int i = 0; i < 8; i++) acc[i] = (floatx4){0, 0, 0, 0};
    {
        const unsigned short* arow = &As[(wave * 16 + lrow) * 200];
        #pragma unroll
        for (int kt = 0; kt < 6; kt++) {
            short8 afrag = *(const short8*)(arow + kt * 32 + quad * 8);
            int kb = kt * 4 + quad;
            #pragma unroll
            for (int nt = 0; nt < 8; nt++) {
                short8 bfrag = *(const short8*)(W1 + (size_t)(kb * 128 + nt * 16 + lrow) * 8);
                acc[nt] = __builtin_amdgcn_mfma_f32_16x16x32_bf16(afrag, bfrag, acc[nt], 0, 0, 0);
            }
        }
    }
    __syncthreads();                         // all As reads done

    // ---- epilogue A: t -> Ts (stride 136, reuses As) ----
    unsigned short* Ts = As;
    #pragma unroll
    for (int nt = 0; nt < 8; nt++) {
        int n = nt * 16 + lrow;
        float bv = b1[n];
        #pragma unroll
        for (int r = 0; r < 4; r++) {
            int el = wave * 16 + quad * 4 + r;
            Ts[el * 136 + n] = f2bf(silu_f(acc[nt][r] + bv));
        }
    }
    __syncthreads();

    // ---- phase B MFMA: K=128, NOUT=128 ----
    floatx4 acc2[8];
    #pragma unroll
    for (int i = 0; i < 8; i++) acc2[i] = (floatx4){0, 0, 0, 0};
    {
        const unsigned short* arow = &Ts[(wave * 16 + lrow) * 136];
        #pragma unroll
        for (int kt = 0; kt < 4; kt++) {
            short8 afrag = *(const short8*)(arow + kt * 32 + quad * 8);
            int kb = kt * 4 + quad;
            #pragma unroll
            for (int nt = 0; nt < 8; nt++) {
                short8 bfrag = *(const short8*)(W2 + (size_t)(kb * 128 + nt * 16 + lrow) * 8);
                acc2[nt] = __builtin_amdgcn_mfma_f32_16x16x32_bf16(afrag, bfrag, acc2[nt], 0, 0, 0);
            }
        }
    }
    __syncthreads();                         // all Ts reads done

    // ---- epilogue B: h_new = acc2 + b2 + resid -> globals + Hs ----
    unsigned short* Hs = As;
    #pragma unroll
    for (int nt = 0; nt < 8; nt++) {
        int n = nt * 16 + lrow;
        float bv = b2[n];
        #pragma unroll
        for (int r = 0; r < 4; r++) {
            int el = wave * 16 + quad * 4 + r;
            int row = m0 + el;
            float v = acc2[nt][r] + bv;
            if (row < M) v += hF[(size_t)row * 128 + n];
            unsigned short vb = f2bf(v);
            Hs[el * 136 + n] = vb;
            if (row < M) {
                hF[(size_t)row * 128 + n] = v;
                hB[(size_t)row * 128 + n] = vb;
            }
        }
    }
    __syncthreads();

    // ---- phase C MFMA: K=128 -> P (128) or out (64) ----
    constexpr int NT3 = FINAL ? 4 : 8;
    constexpr int NO3 = FINAL ? 64 : 128;
    floatx4 acc3[NT3];
    #pragma unroll
    for (int i = 0; i < NT3; i++) acc3[i] = (floatx4){0, 0, 0, 0};
    {
        const unsigned short* arow = &Hs[(wave * 16 + lrow) * 136];
        #pragma unroll
        for (int kt = 0; kt < 4; kt++) {
            short8 afrag = *(const short8*)(arow + kt * 32 + quad * 8);
            int kb = kt * 4 + quad;
            #pragma unroll
            for (int nt = 0; nt < NT3; nt++) {
                short8 bfrag = *(const short8*)(B3 + (size_t)(kb * NO3 + nt * 16 + lrow) * 8);
                acc3[nt] = __builtin_amdgcn_mfma_f32_16x16x32_bf16(afrag, bfrag, acc3[nt], 0, 0, 0);
            }
        }
    }
    #pragma unroll
    for (int nt = 0; nt < NT3; nt++) {
        int n = nt * 16 + lrow;
        float bv = bias3[n];
        #pragma unroll
        for (int r = 0; r < 4; r++) {
            int row = m0 + wave * 16 + quad * 4 + r;
            if (row < M) {
                float v = acc3[nt][r] + bv;
                if (FINAL) outF[(size_t)row * 64 + n] = v;
                else       Pout[(size_t)row * 128 + n] = f2bf(v);
            }
        }
    }
}

// ---------------------------------------------------------------------------
// Fused embedding: h1 = h0 @ W_in + b_in (fp32+bf16), then P0 = h1 @ W1'[0]
// ---------------------------------------------------------------------------
__global__ __launch_bounds__(256) void embed_fused_k(
    const unsigned short* __restrict__ h0bf, const unsigned short* __restrict__ Win,
    const float* __restrict__ b_in, const unsigned short* __restrict__ W1,
    const float* __restrict__ biasP, float* __restrict__ hF,
    unsigned short* __restrict__ hB, unsigned short* __restrict__ Pout, int M)
{
    __shared__ unsigned short As[64 * 136];  // phase 1: stride 72; phase 2: 136
    const int tid = threadIdx.x;
    const int m0 = blockIdx.x * 64;

    for (int t = tid; t < 64 * 8; t += 256) {
        int rr = t >> 3, c = t & 7;
        int row = m0 + rr;
        uintx4 val = {0, 0, 0, 0};
        if (row < M) val = *(const uintx4*)(h0bf + (size_t)row * 64 + c * 8);
        *(uintx4*)(&As[rr * 72 + c * 8]) = val;
    }
    __syncthreads();

    const int wave = tid >> 6;
    const int lane = tid & 63;
    const int lrow = lane & 15;
    const int quad = lane >> 4;

    floatx4 acc[8];
    #pragma unroll
    for (int i = 0; i < 8; i++) acc[i] = (floatx4){0, 0, 0, 0};
    {
        const unsigned short* arow = &As[(wave * 16 + lrow) * 72];
        #pragma unroll
        for (int kt = 0; kt < 2; kt++) {
            short8 afrag = *(const short8*)(arow + kt * 32 + quad * 8);
            int kb = kt * 4 + quad;
            #pragma unroll
            for (int nt = 0; nt < 8; nt++) {
                short8 bfrag = *(const short8*)(Win + (size_t)(kb * 128 + nt * 16 + lrow) * 8);
                acc[nt] = __builtin_amdgcn_mfma_f32_16x16x32_bf16(afrag, bfrag, acc[nt], 0, 0, 0);
            }
        }
    }
    __syncthreads();

    unsigned short* Hs = As;
    #pragma unroll
    for (int nt = 0; nt < 8; nt++) {
        int n = nt * 16 + lrow;
        float bv = b_in[n];
        #pragma unroll
        for (int r = 0; r < 4; r++) {
            int el = wave * 16 + quad * 4 + r;
            int row = m0 + el;
            float v = acc[nt][r] + bv;
            unsigned short vb = f2bf(v);
            Hs[el * 136 + n] = vb;
            if (row < M) {
                hF[(size_t)row * 128 + n] = v;
                hB[(size_t)row * 128 + n] = vb;
            }
        }
    }
    __syncthreads();

    floatx4 acc3[8];
    #pragma unroll
    for (int i = 0; i < 8; i++) acc3[i] = (floatx4){0, 0, 0, 0};
    {
        const unsigned short* arow = &Hs[(wave * 16 + lrow) * 136];
        #pragma unroll
        for (int kt = 0; kt < 4; kt++) {
            short8 afrag = *(const short8*)(arow + kt * 32 + quad * 8);
            int kb = kt * 4 + quad;
            #pragma unroll
            for (int nt = 0; nt < 8; nt++) {
                short8 bfrag = *(const short8*)(W1 + (size_t)(kb * 128 + nt * 16 + lrow) * 8);
                acc3[nt] = __builtin_amdgcn_mfma_f32_16x16x32_bf16(afrag, bfrag, acc3[nt], 0, 0, 0);
            }
        }
    }
    #pragma unroll
    for (int nt = 0; nt < 8; nt++) {
        int n = nt * 16 + lrow;
        float bv = biasP[n];
        #pragma unroll
        for (int r = 0; r < 4; r++) {
            int row = m0 + wave * 16 + quad * 4 + r;
            if (row < M) Pout[(size_t)row * 128 + n] = f2bf(acc3[nt][r] + bv);
        }
    }
}

// ---------------------------------------------------------------------------
extern "C" void kernel_launch(void* const* d_in, const int* in_sizes, int n_in,
                              void* d_out, int out_size, void* d_ws, size_t ws_size,
                              hipStream_t stream) {
    const float* h0   = (const float*)d_in[0];
    const int*   edges= (const int*)d_in[1];
    const float* W_in = (const float*)d_in[2];
    const float* b_in = (const float*)d_in[3];
    const float* eW1  = (const float*)d_in[4];
    const float* eb1  = (const float*)d_in[5];
    const float* eW2  = (const float*)d_in[6];
    const float* eb2  = (const float*)d_in[7];
    const float* nW1  = (const float*)d_in[8];
    const float* nb1  = (const float*)d_in[9];
    const float* nW2  = (const float*)d_in[10];
    const float* nb2  = (const float*)d_in[11];
    const float* W_out= (const float*)d_in[12];
    const float* b_out= (const float*)d_in[13];
    float* out = (float*)d_out;

    const int E = in_sizes[1] / 2;      // 800000
    const int* erow = edges;
    const int* ecol = edges + E;

    char* ws = (char*)d_ws;
    unsigned short* hbf  = (unsigned short*)(ws + 0);            // 12,800,000
    float*          hbufF= (float*)(ws + 12800000);              // 25,600,000
    unsigned short* P    = (unsigned short*)(ws + 38400000);     // 12,800,000
    float*          agg  = (float*)(ws + 51200000);              // 12,800,000
    // 64,000,000..76,800,000 free (was tbuf)
    unsigned short* h0bf = (unsigned short*)(ws + 76800000);     //  6,400,000 (start only)
    int*            rowS = (int*)(ws + 76800000);                //  3,200,000 (aliases h0bf)
    int*            colS = (int*)(ws + 80000000);                //  3,200,000
    float*          biasP= (float*)(ws + 83200000);              //  2,048
    unsigned short* Winp = (unsigned short*)(ws + 83202048);     // 16,384
    unsigned short* Woutp= (unsigned short*)(ws + 83218432);     // 16,384
    unsigned short* W1p  = (unsigned short*)(ws + 83234816);     // 131,072
    unsigned short* eW2p = (unsigned short*)(ws + 83365888);     // 32,768
    unsigned short* nW1p = (unsigned short*)(ws + 83398656);     // 196,608
    unsigned short* nW2p = (unsigned short*)(ws + 83595264);     // 131,072
    int*            counts=(int*)(ws + 83726336);                // 200,000
    int*            cursor=(int*)(ws + 83926336);                // 200,000
    int*            bsum = (int*)(ws + 84126336);                // 256

    const int gemm_grid = (N_NODES + 63) / 64;    // 782
    const int edge_grid = (E + 63) / 64;          // 12500
    const int pack_grid = (int)((PACK_TOTAL + 255) / 256);
    const int nb = (N_NODES + 1023) / 1024;       // 49

    pack_kernel<<<pack_grid, 256, 0, stream>>>(h0, W_in, W_out, eW1, eb1, eW2,
                                               nW1, nW2, h0bf, Winp, Woutp, W1p,
                                               eW2p, nW1p, nW2p, biasP);

    // h1 = h0 @ W_in + b_in; P0 = h1 @ W1'[0]   (reads h0bf before scatter reuse)
    embed_fused_k<<<gemm_grid, 256, 0, stream>>>(
        h0bf, Winp, b_in, W1p, biasP, hbufF, hbf, P, N_NODES);

    // CSR build
    hipMemsetAsync(counts, 0, (size_t)N_NODES * 4, stream);
    hist_k<<<(E + 255) / 256, 256, 0, stream>>>(erow, counts, E);
    scan1_k<<<nb, 1024, 0, stream>>>(counts, cursor, bsum, N_NODES);
    scan2_k<<<1, 64, 0, stream>>>(bsum, nb);
    scan3_k<<<nb, 1024, 0, stream>>>(cursor, bsum, N_NODES);
    scatter_k<<<(E + 255) / 256, 256, 0, stream>>>(erow, ecol, cursor, rowS, colS, E);

    for (int l = 0; l < 4; l++) {
        hipMemsetAsync(agg, 0, (size_t)N_NODES * 64 * 4, stream);
        edge_fused_k<<<edge_grid, 256, 0, stream>>>(
            rowS, colS, P, eW2p + (size_t)l * SE2, eb2 + (size_t)l * 64, agg, E);
        if (l < 3) {
            node_fused_k<0><<<gemm_grid, 256, 0, stream>>>(
                hbf, agg, nW1p + (size_t)l * SN1, nb1 + (size_t)l * 128,
                nW2p + (size_t)l * SN2, nb2 + (size_t)l * 128,
                W1p + (size_t)(l + 1) * SW1, biasP + (size_t)(l + 1) * 128,
                hbufF, hbf, P, nullptr, N_NODES);
        } else {
            node_fused_k<1><<<gemm_grid, 256, 0, stream>>>(
                hbf, agg, nW1p + (size_t)l * SN1, nb1 + (size_t)l * 128,
                nW2p + (size_t)l * SN2, nb2 + (size_t)l * 128,
                Woutp, b_out, hbufF, hbf, nullptr, out, N_NODES);
        }
    }
}